// Round 1
// baseline (10966.219 us; speedup 1.0000x reference)
//
#include <hip/hip_runtime.h>

#define D 256

// ---------------------------------------------------------------------------
// Kernel 1: h = x @ W^T + b   (f32, h[i][j] = b[j] + sum_k x[i][k] * W[j][k])
// 256 threads/block, ROWS rows of x staged in LDS, thread j owns column j.
// W rows are read per-thread (uncoalesced but W = 256 KB -> L2-resident).
// ---------------------------------------------------------------------------
template <int ROWS>
__global__ __launch_bounds__(256) void linear_kernel(
    const float* __restrict__ x, const float* __restrict__ W,
    const float* __restrict__ b, float* __restrict__ h, int n)
{
    __shared__ float xs[ROWS][D];
    const int tid = threadIdx.x;
    const int row0 = blockIdx.x * ROWS;

    // cooperative load of x tile: thread t loads row (t>>6)+4k, float4 col (t&63)
    const int c4 = tid & 63;
    for (int rr = (tid >> 6); rr < ROWS; rr += 4) {
        const int grow = row0 + rr;
        float4 v = make_float4(0.f, 0.f, 0.f, 0.f);
        if (grow < n) v = ((const float4*)(x + (size_t)grow * D))[c4];
        ((float4*)&xs[rr][0])[c4] = v;
    }
    __syncthreads();

    const int j = tid;  // output column
    float acc[ROWS];
#pragma unroll
    for (int i = 0; i < ROWS; ++i) acc[i] = 0.f;

    const float4* __restrict__ W4 = (const float4*)(W + (size_t)j * D);
    for (int k4 = 0; k4 < D / 4; ++k4) {
        const float4 w = W4[k4];
#pragma unroll
        for (int i = 0; i < ROWS; ++i) {
            const float4 xv = ((const float4*)&xs[i][0])[k4];  // LDS broadcast
            acc[i] += xv.x * w.x + xv.y * w.y + xv.z * w.z + xv.w * w.w;
        }
    }

    const float bj = b[j];
    for (int i = 0; i < ROWS; ++i) {
        const int grow = row0 + i;
        if (grow < n) h[(size_t)grow * D + j] = acc[i] + bj;
    }
}

// ---------------------------------------------------------------------------
// Kernel 2: per-edge scatter. One wave per edge: lane l loads float4 of
// h[col], scales by val, atomically adds into out[row].
// ---------------------------------------------------------------------------
__global__ __launch_bounds__(256) void scatter_kernel(
    const int* __restrict__ adj_row, const int* __restrict__ adj_col,
    const float* __restrict__ adj_vals, const float* __restrict__ h,
    float* __restrict__ out, int E)
{
    const int wave = blockIdx.x * 4 + (threadIdx.x >> 6);
    const int lane = threadIdx.x & 63;
    if (wave >= E) return;

    const int r = adj_row[wave];
    const int c = adj_col[wave];
    const float v = adj_vals[wave];

    const float4 hv = ((const float4*)(h + (size_t)c * D))[lane];
    float* op = out + (size_t)r * D + lane * 4;
    unsafeAtomicAdd(op + 0, hv.x * v);
    unsafeAtomicAdd(op + 1, hv.y * v);
    unsafeAtomicAdd(op + 2, hv.z * v);
    unsafeAtomicAdd(op + 3, hv.w * v);
}

// ---------------------------------------------------------------------------
// Kernel 3: in-place ReLU, float4 grid-stride.
// ---------------------------------------------------------------------------
__global__ __launch_bounds__(256) void relu_kernel(float* __restrict__ out, int n4)
{
    int i = blockIdx.x * blockDim.x + threadIdx.x;
    const int stride = gridDim.x * blockDim.x;
    for (; i < n4; i += stride) {
        float4 v = ((const float4*)out)[i];
        v.x = fmaxf(v.x, 0.f);
        v.y = fmaxf(v.y, 0.f);
        v.z = fmaxf(v.z, 0.f);
        v.w = fmaxf(v.w, 0.f);
        ((float4*)out)[i] = v;
    }
}

extern "C" void kernel_launch(void* const* d_in, const int* in_sizes, int n_in,
                              void* d_out, int out_size, void* d_ws, size_t ws_size,
                              hipStream_t stream)
{
    const float* x        = (const float*)d_in[0];
    const int*   adj_row  = (const int*)d_in[1];
    const int*   adj_col  = (const int*)d_in[2];
    const float* adj_vals = (const float*)d_in[3];
    const float* W        = (const float*)d_in[4];
    const float* b        = (const float*)d_in[5];
    float*       out      = (float*)d_out;
    float*       h        = (float*)d_ws;  // needs N*256*4 = 102.4 MB scratch

    const int n = in_sizes[0] / D;   // 100000 nodes
    const int E = in_sizes[1];       // 3.2M edges

    // out must start at zero every call (harness poisons once, never re-zeros)
    hipMemsetAsync(d_out, 0, (size_t)out_size * sizeof(float), stream);

    constexpr int ROWS = 32;
    linear_kernel<ROWS><<<(n + ROWS - 1) / ROWS, 256, 0, stream>>>(x, W, b, h, n);
    scatter_kernel<<<(E + 3) / 4, 256, 0, stream>>>(adj_row, adj_col, adj_vals, h, out, E);
    relu_kernel<<<2048, 256, 0, stream>>>(out, out_size / 4);
}

// Round 2
// 1088.787 us; speedup vs baseline: 10.0720x; 10.0720x over previous
//
#include <hip/hip_runtime.h>

#define D 256

// ---------------------------------------------------------------------------
// Kernel 1: h = x @ W^T + b   (f32)
// ---------------------------------------------------------------------------
template <int ROWS>
__global__ __launch_bounds__(256) void linear_kernel(
    const float* __restrict__ x, const float* __restrict__ W,
    const float* __restrict__ b, float* __restrict__ h, int n)
{
    __shared__ float xs[ROWS][D];
    const int tid = threadIdx.x;
    const int row0 = blockIdx.x * ROWS;

    const int c4 = tid & 63;
    for (int rr = (tid >> 6); rr < ROWS; rr += 4) {
        const int grow = row0 + rr;
        float4 v = make_float4(0.f, 0.f, 0.f, 0.f);
        if (grow < n) v = ((const float4*)(x + (size_t)grow * D))[c4];
        ((float4*)&xs[rr][0])[c4] = v;
    }
    __syncthreads();

    const int j = tid;
    float acc[ROWS];
#pragma unroll
    for (int i = 0; i < ROWS; ++i) acc[i] = 0.f;

    const float4* __restrict__ W4 = (const float4*)(W + (size_t)j * D);
    for (int k4 = 0; k4 < D / 4; ++k4) {
        const float4 w = W4[k4];
#pragma unroll
        for (int i = 0; i < ROWS; ++i) {
            const float4 xv = ((const float4*)&xs[i][0])[k4];
            acc[i] += xv.x * w.x + xv.y * w.y + xv.z * w.z + xv.w * w.w;
        }
    }

    const float bj = b[j];
    for (int i = 0; i < ROWS; ++i) {
        const int grow = row0 + i;
        if (grow < n) h[(size_t)grow * D + j] = acc[i] + bj;
    }
}

// ---------------------------------------------------------------------------
// CSR build: histogram -> scan -> fill
// ---------------------------------------------------------------------------
__global__ __launch_bounds__(256) void count_rows(
    const int* __restrict__ rows, int* __restrict__ counts, int E)
{
    int i = blockIdx.x * 256 + threadIdx.x;
    const int stride = gridDim.x * 256;
    for (; i < E; i += stride) atomicAdd(&counts[rows[i]], 1);
}

// per-block (1024-element) exclusive scan, in place; block totals out.
__global__ __launch_bounds__(256) void scan_blocks(
    int* __restrict__ data, int* __restrict__ bsums, int n)
{
    __shared__ int wsums[4];
    const int tid = threadIdx.x;
    const int lane = tid & 63;
    const int wid = tid >> 6;
    const int base = blockIdx.x * 1024 + tid * 4;

    int c0 = 0, c1 = 0, c2 = 0, c3 = 0;
    if (base + 0 < n) c0 = data[base + 0];
    if (base + 1 < n) c1 = data[base + 1];
    if (base + 2 < n) c2 = data[base + 2];
    if (base + 3 < n) c3 = data[base + 3];
    const int tsum = c0 + c1 + c2 + c3;

    int v = tsum;
    for (int d = 1; d < 64; d <<= 1) {
        int u = __shfl_up(v, d, 64);
        if (lane >= d) v += u;
    }
    if (lane == 63) wsums[wid] = v;
    __syncthreads();

    int woff = 0;
    for (int w = 0; w < wid; ++w) woff += wsums[w];

    int run = woff + (v - tsum);  // exclusive prefix for this thread
    if (base + 0 < n) data[base + 0] = run; run += c0;
    if (base + 1 < n) data[base + 1] = run; run += c1;
    if (base + 2 < n) data[base + 2] = run; run += c2;
    if (base + 3 < n) data[base + 3] = run;

    if (tid == 0) bsums[blockIdx.x] = wsums[0] + wsums[1] + wsums[2] + wsums[3];
}

__global__ void scan_bsums(int* __restrict__ bsums, int nb)
{
    if (threadIdx.x == 0 && blockIdx.x == 0) {
        int run = 0;
        for (int i = 0; i < nb; ++i) { int t = bsums[i]; bsums[i] = run; run += t; }
    }
}

__global__ __launch_bounds__(256) void finalize_rowptr(
    int* __restrict__ row_ptr, int* __restrict__ cursor,
    const int* __restrict__ bsums, int n, int E)
{
    const int i = blockIdx.x * 256 + threadIdx.x;
    if (i < n) {
        const int v = row_ptr[i] + bsums[i >> 10];
        row_ptr[i] = v;
        cursor[i] = v;
    }
    if (i == 0) row_ptr[n] = E;
}

__global__ __launch_bounds__(256) void fill_csr(
    const int* __restrict__ adj_row, const int* __restrict__ adj_col,
    const float* __restrict__ adj_vals, int* __restrict__ cursor,
    int2* __restrict__ csr, int E)
{
    int i = blockIdx.x * 256 + threadIdx.x;
    const int stride = gridDim.x * 256;
    for (; i < E; i += stride) {
        const int r = adj_row[i];
        const int pos = atomicAdd(&cursor[r], 1);
        csr[pos] = make_int2(adj_col[i], __float_as_int(adj_vals[i]));
    }
}

// ---------------------------------------------------------------------------
// Gather-reduce: one wave per row. Lane l owns float4 l of the 256-wide row.
// out[row] = relu(sum_e val_e * h[col_e]); every out row written exactly once.
// ---------------------------------------------------------------------------
__global__ __launch_bounds__(256) void gather_reduce(
    const int* __restrict__ row_ptr, const int2* __restrict__ csr,
    const float* __restrict__ h, float* __restrict__ out, int n)
{
    const int row = blockIdx.x * 4 + (threadIdx.x >> 6);
    if (row >= n) return;
    const int lane = threadIdx.x & 63;

    const int s = row_ptr[row];
    const int e = row_ptr[row + 1];

    float4 acc = make_float4(0.f, 0.f, 0.f, 0.f);
    int i = s;
    for (; i + 1 < e; i += 2) {                 // unroll 2: two gathers in flight
        const int2 cv0 = csr[i];
        const int2 cv1 = csr[i + 1];
        const float4 h0 = ((const float4*)(h + (size_t)cv0.x * D))[lane];
        const float4 h1 = ((const float4*)(h + (size_t)cv1.x * D))[lane];
        const float v0 = __int_as_float(cv0.y);
        const float v1 = __int_as_float(cv1.y);
        acc.x += v0 * h0.x + v1 * h1.x;
        acc.y += v0 * h0.y + v1 * h1.y;
        acc.z += v0 * h0.z + v1 * h1.z;
        acc.w += v0 * h0.w + v1 * h1.w;
    }
    if (i < e) {
        const int2 cv = csr[i];
        const float v = __int_as_float(cv.y);
        const float4 hv = ((const float4*)(h + (size_t)cv.x * D))[lane];
        acc.x += v * hv.x; acc.y += v * hv.y;
        acc.z += v * hv.z; acc.w += v * hv.w;
    }

    acc.x = fmaxf(acc.x, 0.f); acc.y = fmaxf(acc.y, 0.f);
    acc.z = fmaxf(acc.z, 0.f); acc.w = fmaxf(acc.w, 0.f);
    ((float4*)(out + (size_t)row * D))[lane] = acc;
}

// ---------------------------------------------------------------------------
// Fallback (ws too small): atomic scatter path from R1.
// ---------------------------------------------------------------------------
__global__ __launch_bounds__(256) void scatter_kernel(
    const int* __restrict__ adj_row, const int* __restrict__ adj_col,
    const float* __restrict__ adj_vals, const float* __restrict__ h,
    float* __restrict__ out, int E)
{
    const int wave = blockIdx.x * 4 + (threadIdx.x >> 6);
    const int lane = threadIdx.x & 63;
    if (wave >= E) return;
    const int r = adj_row[wave];
    const int c = adj_col[wave];
    const float v = adj_vals[wave];
    const float4 hv = ((const float4*)(h + (size_t)c * D))[lane];
    float* op = out + (size_t)r * D + lane * 4;
    unsafeAtomicAdd(op + 0, hv.x * v);
    unsafeAtomicAdd(op + 1, hv.y * v);
    unsafeAtomicAdd(op + 2, hv.z * v);
    unsafeAtomicAdd(op + 3, hv.w * v);
}

__global__ __launch_bounds__(256) void relu_kernel(float* __restrict__ out, int n4)
{
    int i = blockIdx.x * blockDim.x + threadIdx.x;
    const int stride = gridDim.x * blockDim.x;
    for (; i < n4; i += stride) {
        float4 v = ((const float4*)out)[i];
        v.x = fmaxf(v.x, 0.f); v.y = fmaxf(v.y, 0.f);
        v.z = fmaxf(v.z, 0.f); v.w = fmaxf(v.w, 0.f);
        ((float4*)out)[i] = v;
    }
}

// ---------------------------------------------------------------------------
extern "C" void kernel_launch(void* const* d_in, const int* in_sizes, int n_in,
                              void* d_out, int out_size, void* d_ws, size_t ws_size,
                              hipStream_t stream)
{
    const float* x        = (const float*)d_in[0];
    const int*   adj_row  = (const int*)d_in[1];
    const int*   adj_col  = (const int*)d_in[2];
    const float* adj_vals = (const float*)d_in[3];
    const float* W        = (const float*)d_in[4];
    const float* b        = (const float*)d_in[5];
    float*       out      = (float*)d_out;

    const int n = in_sizes[0] / D;   // 100000 nodes
    const int E = in_sizes[1];       // 3.2M edges
    const int NB = (n + 1023) / 1024;

    // workspace layout (256B-aligned chunks)
    char* ws = (char*)d_ws;
    size_t off = 0;
    auto alloc = [&](size_t bytes) {
        size_t o = off;
        off += (bytes + 255) & ~(size_t)255;
        return o;
    };
    float* h       = (float*)(ws + alloc((size_t)n * D * sizeof(float)));
    int*   row_ptr = (int*)  (ws + alloc((size_t)(n + 1) * sizeof(int)));
    int*   cursor  = (int*)  (ws + alloc((size_t)n * sizeof(int)));
    int*   bsums   = (int*)  (ws + alloc((size_t)NB * sizeof(int)));
    int2*  csr     = (int2*) (ws + alloc((size_t)E * sizeof(int2)));
    const size_t needed = off;

    constexpr int ROWS = 32;
    linear_kernel<ROWS><<<(n + ROWS - 1) / ROWS, 256, 0, stream>>>(x, W, b, h, n);

    if (ws_size >= needed) {
        // CSR build
        hipMemsetAsync(row_ptr, 0, (size_t)(n + 1) * sizeof(int), stream);
        count_rows<<<2048, 256, 0, stream>>>(adj_row, row_ptr, E);
        scan_blocks<<<NB, 256, 0, stream>>>(row_ptr, bsums, n);
        scan_bsums<<<1, 64, 0, stream>>>(bsums, NB);
        finalize_rowptr<<<(n + 255) / 256, 256, 0, stream>>>(row_ptr, cursor, bsums, n, E);
        fill_csr<<<2048, 256, 0, stream>>>(adj_row, adj_col, adj_vals, cursor, csr, E);
        // fused gather + ReLU (writes every out element; no memset needed)
        gather_reduce<<<(n + 3) / 4, 256, 0, stream>>>(row_ptr, csr, h, out, n);
    } else {
        // fallback: atomic scatter
        hipMemsetAsync(d_out, 0, (size_t)out_size * sizeof(float), stream);
        scatter_kernel<<<(E + 3) / 4, 256, 0, stream>>>(adj_row, adj_col, adj_vals, h, out, E);
        relu_kernel<<<2048, 256, 0, stream>>>(out, out_size / 4);
    }
}

// Round 3
// 672.905 us; speedup vs baseline: 16.2968x; 1.6180x over previous
//
#include <hip/hip_runtime.h>

#define D 256

typedef __attribute__((ext_vector_type(8))) short bf16x8;
typedef __attribute__((ext_vector_type(4))) float f32x4;

static __device__ __forceinline__ unsigned short f2bf(float f) {
    unsigned u = __float_as_uint(f);
    u += 0x7FFF + ((u >> 16) & 1);   // round-to-nearest-even
    return (unsigned short)(u >> 16);
}
static __device__ __forceinline__ float bf_lo(unsigned u) {
    return __uint_as_float(u << 16);
}
static __device__ __forceinline__ float bf_hi(unsigned u) {
    return __uint_as_float(u & 0xFFFF0000u);
}

// ---------------------------------------------------------------------------
// pack W (f32 [N=256][K=256], row n, col k) into MFMA-B fragment order, bf16:
// frag t = (kt*16+nt)*64+lane holds 8 bf16: B[k][n] = W[n][k],
// n = nt*16 + (lane&15), k = kt*32 + (lane>>4)*8 + j.
// ---------------------------------------------------------------------------
__global__ __launch_bounds__(256) void pack_W(
    const float* __restrict__ W, unsigned short* __restrict__ Wp)
{
    const int t = blockIdx.x * 256 + threadIdx.x;   // 0..8191
    const int lane = t & 63;
    const int nt = (t >> 6) & 15;
    const int kt = t >> 10;
    const int n = nt * 16 + (lane & 15);
    const int k0 = kt * 32 + (lane >> 4) * 8;
#pragma unroll
    for (int j = 0; j < 8; ++j)
        Wp[(size_t)t * 8 + j] = f2bf(W[n * D + k0 + j]);
}

// ---------------------------------------------------------------------------
// h = bf16(x @ W^T + b) via MFMA 16x16x32 bf16.
// Block: 256 thr = 4 waves, 128 rows/block; wave owns 32 rows x 256 cols.
// A frags loaded from global f32 x and converted in-register.
// B frags from fragment-packed Wp (L2-resident, 128 KB).
// ---------------------------------------------------------------------------
__global__ __launch_bounds__(256) void mfma_linear(
    const float* __restrict__ x, const unsigned short* __restrict__ Wp,
    const float* __restrict__ b, unsigned short* __restrict__ h, int M)
{
    const int lane = threadIdx.x & 63;
    const int wave = threadIdx.x >> 6;
    const int row0 = blockIdx.x * 128 + wave * 32;
    const int arow = lane & 15;
    const int kgrp = lane >> 4;   // 0..3

    f32x4 acc[2][16];
#pragma unroll
    for (int t = 0; t < 2; ++t)
#pragma unroll
        for (int nt = 0; nt < 16; ++nt)
            acc[t][nt] = (f32x4){0.f, 0.f, 0.f, 0.f};

    for (int kt = 0; kt < 8; ++kt) {
        const int k0 = kt * 32 + kgrp * 8;
        bf16x8 a[2];
#pragma unroll
        for (int t = 0; t < 2; ++t) {
            int r = row0 + t * 16 + arow;
            if (r >= M) r = M - 1;                       // clamp; store guarded
            const float4* xp = (const float4*)(x + (size_t)r * D + k0);
            const float4 lo = xp[0];
            const float4 hi = xp[1];
            a[t][0] = (short)f2bf(lo.x); a[t][1] = (short)f2bf(lo.y);
            a[t][2] = (short)f2bf(lo.z); a[t][3] = (short)f2bf(lo.w);
            a[t][4] = (short)f2bf(hi.x); a[t][5] = (short)f2bf(hi.y);
            a[t][6] = (short)f2bf(hi.z); a[t][7] = (short)f2bf(hi.w);
        }
        const bf16x8* __restrict__ wp =
            (const bf16x8*)Wp + (size_t)(kt * 16) * 64 + lane;
#pragma unroll
        for (int nt = 0; nt < 16; ++nt) {
            const bf16x8 bf = wp[nt * 64];
            acc[0][nt] = __builtin_amdgcn_mfma_f32_16x16x32_bf16(a[0], bf, acc[0][nt], 0, 0, 0);
            acc[1][nt] = __builtin_amdgcn_mfma_f32_16x16x32_bf16(a[1], bf, acc[1][nt], 0, 0, 0);
        }
    }

    // C/D layout: col = lane&15, row = (lane>>4)*4 + reg   [m89-verified]
    const int crow = (lane >> 4) * 4;
    const int ccol = lane & 15;
#pragma unroll
    for (int t = 0; t < 2; ++t)
#pragma unroll
        for (int nt = 0; nt < 16; ++nt) {
            const float bj = b[nt * 16 + ccol];
#pragma unroll
            for (int r = 0; r < 4; ++r) {
                const int row = row0 + t * 16 + crow + r;
                if (row < M)
                    h[(size_t)row * D + nt * 16 + ccol] = f2bf(acc[t][nt][r] + bj);
            }
        }
}

// ---------------------------------------------------------------------------
// CSR build: histogram -> scan -> fill
// ---------------------------------------------------------------------------
__global__ __launch_bounds__(256) void count_rows(
    const int* __restrict__ rows, int* __restrict__ counts, int E)
{
    int i = blockIdx.x * 256 + threadIdx.x;
    const int stride = gridDim.x * 256;
    for (; i < E; i += stride) atomicAdd(&counts[rows[i]], 1);
}

__global__ __launch_bounds__(256) void scan_blocks(
    int* __restrict__ data, int* __restrict__ bsums, int n)
{
    __shared__ int wsums[4];
    const int tid = threadIdx.x;
    const int lane = tid & 63;
    const int wid = tid >> 6;
    const int base = blockIdx.x * 1024 + tid * 4;

    int c0 = 0, c1 = 0, c2 = 0, c3 = 0;
    if (base + 0 < n) c0 = data[base + 0];
    if (base + 1 < n) c1 = data[base + 1];
    if (base + 2 < n) c2 = data[base + 2];
    if (base + 3 < n) c3 = data[base + 3];
    const int tsum = c0 + c1 + c2 + c3;

    int v = tsum;
    for (int d = 1; d < 64; d <<= 1) {
        int u = __shfl_up(v, d, 64);
        if (lane >= d) v += u;
    }
    if (lane == 63) wsums[wid] = v;
    __syncthreads();

    int woff = 0;
    for (int w = 0; w < wid; ++w) woff += wsums[w];

    int run = woff + (v - tsum);
    if (base + 0 < n) data[base + 0] = run; run += c0;
    if (base + 1 < n) data[base + 1] = run; run += c1;
    if (base + 2 < n) data[base + 2] = run; run += c2;
    if (base + 3 < n) data[base + 3] = run;

    if (tid == 0) bsums[blockIdx.x] = wsums[0] + wsums[1] + wsums[2] + wsums[3];
}

__global__ void scan_bsums(int* __restrict__ bsums, int nb)
{
    if (threadIdx.x == 0 && blockIdx.x == 0) {
        int run = 0;
        for (int i = 0; i < nb; ++i) { int t = bsums[i]; bsums[i] = run; run += t; }
    }
}

__global__ __launch_bounds__(256) void finalize_rowptr(
    int* __restrict__ row_ptr, int* __restrict__ cursor,
    const int* __restrict__ bsums, int n, int E)
{
    const int i = blockIdx.x * 256 + threadIdx.x;
    if (i < n) {
        const int v = row_ptr[i] + bsums[i >> 10];
        row_ptr[i] = v;
        cursor[i] = v;
    }
    if (i == 0) row_ptr[n] = E;
}

__global__ __launch_bounds__(256) void fill_csr(
    const int* __restrict__ adj_row, const int* __restrict__ adj_col,
    const float* __restrict__ adj_vals, int* __restrict__ cursor,
    int2* __restrict__ csr, int E)
{
    int i = blockIdx.x * 256 + threadIdx.x;
    const int stride = gridDim.x * 256;
    for (; i < E; i += stride) {
        const int r = adj_row[i];
        const int pos = atomicAdd(&cursor[r], 1);
        csr[pos] = make_int2(adj_col[i], __float_as_int(adj_vals[i]));
    }
}

// ---------------------------------------------------------------------------
// Gather-reduce over bf16 h: one wave per row, lane owns 4 cols (8B/edge).
// f32 accumulate, fused ReLU, single f32 write of out row.
// ---------------------------------------------------------------------------
__global__ __launch_bounds__(256) void gather_bf16(
    const int* __restrict__ row_ptr, const int2* __restrict__ csr,
    const unsigned short* __restrict__ h, float* __restrict__ out, int n)
{
    const int row = blockIdx.x * 4 + (threadIdx.x >> 6);
    if (row >= n) return;
    const int lane = threadIdx.x & 63;

    const int s = row_ptr[row];
    const int e = row_ptr[row + 1];

    float a0 = 0.f, a1 = 0.f, a2 = 0.f, a3 = 0.f;

    int i = s;
    for (; i + 4 <= e; i += 4) {
        const int2 c0 = csr[i + 0];
        const int2 c1 = csr[i + 1];
        const int2 c2 = csr[i + 2];
        const int2 c3 = csr[i + 3];
        const uint2 d0 = ((const uint2*)(h + (size_t)c0.x * D))[lane];
        const uint2 d1 = ((const uint2*)(h + (size_t)c1.x * D))[lane];
        const uint2 d2 = ((const uint2*)(h + (size_t)c2.x * D))[lane];
        const uint2 d3 = ((const uint2*)(h + (size_t)c3.x * D))[lane];
        const float v0 = __int_as_float(c0.y);
        const float v1 = __int_as_float(c1.y);
        const float v2 = __int_as_float(c2.y);
        const float v3 = __int_as_float(c3.y);
        a0 += v0 * bf_lo(d0.x) + v1 * bf_lo(d1.x) + v2 * bf_lo(d2.x) + v3 * bf_lo(d3.x);
        a1 += v0 * bf_hi(d0.x) + v1 * bf_hi(d1.x) + v2 * bf_hi(d2.x) + v3 * bf_hi(d3.x);
        a2 += v0 * bf_lo(d0.y) + v1 * bf_lo(d1.y) + v2 * bf_lo(d2.y) + v3 * bf_lo(d3.y);
        a3 += v0 * bf_hi(d0.y) + v1 * bf_hi(d1.y) + v2 * bf_hi(d2.y) + v3 * bf_hi(d3.y);
    }
    for (; i < e; ++i) {
        const int2 cv = csr[i];
        const uint2 dv = ((const uint2*)(h + (size_t)cv.x * D))[lane];
        const float v = __int_as_float(cv.y);
        a0 += v * bf_lo(dv.x);
        a1 += v * bf_hi(dv.x);
        a2 += v * bf_lo(dv.y);
        a3 += v * bf_hi(dv.y);
    }

    float4 st;
    st.x = fmaxf(a0, 0.f); st.y = fmaxf(a1, 0.f);
    st.z = fmaxf(a2, 0.f); st.w = fmaxf(a3, 0.f);
    ((float4*)(out + (size_t)row * D))[lane] = st;
}

// ---------------------------------------------------------------------------
extern "C" void kernel_launch(void* const* d_in, const int* in_sizes, int n_in,
                              void* d_out, int out_size, void* d_ws, size_t ws_size,
                              hipStream_t stream)
{
    const float* x        = (const float*)d_in[0];
    const int*   adj_row  = (const int*)d_in[1];
    const int*   adj_col  = (const int*)d_in[2];
    const float* adj_vals = (const float*)d_in[3];
    const float* W        = (const float*)d_in[4];
    const float* b        = (const float*)d_in[5];
    float*       out      = (float*)d_out;

    const int n = in_sizes[0] / D;   // 100000 nodes
    const int E = in_sizes[1];       // 3.2M edges
    const int NB = (n + 1023) / 1024;

    char* ws = (char*)d_ws;
    size_t off = 0;
    auto alloc = [&](size_t bytes) {
        size_t o = off;
        off += (bytes + 255) & ~(size_t)255;
        return o;
    };
    unsigned short* h  = (unsigned short*)(ws + alloc((size_t)n * D * sizeof(unsigned short)));
    unsigned short* Wp = (unsigned short*)(ws + alloc((size_t)8192 * 8 * sizeof(unsigned short)));
    int*   row_ptr = (int*) (ws + alloc((size_t)(n + 1) * sizeof(int)));
    int*   cursor  = (int*) (ws + alloc((size_t)n * sizeof(int)));
    int*   bsums   = (int*) (ws + alloc((size_t)NB * sizeof(int)));
    int2*  csr     = (int2*)(ws + alloc((size_t)E * sizeof(int2)));
    (void)ws_size;

    // linear: pack W, then MFMA GEMM into bf16 h
    pack_W<<<32, 256, 0, stream>>>(W, Wp);
    mfma_linear<<<(n + 127) / 128, 256, 0, stream>>>(x, Wp, b, h, n);

    // CSR build
    hipMemsetAsync(row_ptr, 0, (size_t)(n + 1) * sizeof(int), stream);
    count_rows<<<2048, 256, 0, stream>>>(adj_row, row_ptr, E);
    scan_blocks<<<NB, 256, 0, stream>>>(row_ptr, bsums, n);
    scan_bsums<<<1, 64, 0, stream>>>(bsums, NB);
    finalize_rowptr<<<(n + 255) / 256, 256, 0, stream>>>(row_ptr, cursor, bsums, n, E);
    fill_csr<<<2048, 256, 0, stream>>>(adj_row, adj_col, adj_vals, cursor, csr, E);

    // fused gather + ReLU (writes every out element; no memset needed)
    gather_bf16<<<(n + 3) / 4, 256, 0, stream>>>(row_ptr, csr, h, out, n);
}

// Round 4
// 590.785 us; speedup vs baseline: 18.5621x; 1.1390x over previous
//
#include <hip/hip_runtime.h>

#define D 256
#define BSHIFT 9
#define BROWS 512            // rows per bucket
#define MAXBK 256            // supports n <= 131072

typedef __attribute__((ext_vector_type(8))) short bf16x8;
typedef __attribute__((ext_vector_type(4))) float f32x4;

static __device__ __forceinline__ unsigned short f2bf(float f) {
    unsigned u = __float_as_uint(f);
    u += 0x7FFF + ((u >> 16) & 1);   // round-to-nearest-even
    return (unsigned short)(u >> 16);
}
static __device__ __forceinline__ float bf_lo(unsigned u) {
    return __uint_as_float(u << 16);
}
static __device__ __forceinline__ float bf_hi(unsigned u) {
    return __uint_as_float(u & 0xFFFF0000u);
}

// ---------------------------------------------------------------------------
// pack W (f32 [256][256]) into MFMA-B fragment order, bf16.
// ---------------------------------------------------------------------------
__global__ __launch_bounds__(256) void pack_W(
    const float* __restrict__ W, unsigned short* __restrict__ Wp)
{
    const int t = blockIdx.x * 256 + threadIdx.x;   // 0..8191
    const int lane = t & 63;
    const int nt = (t >> 6) & 15;
    const int kt = t >> 10;
    const int n = nt * 16 + (lane & 15);
    const int k0 = kt * 32 + (lane >> 4) * 8;
#pragma unroll
    for (int j = 0; j < 8; ++j)
        Wp[(size_t)t * 8 + j] = f2bf(W[n * D + k0 + j]);
}

// ---------------------------------------------------------------------------
// h = bf16(x @ W^T + b) via MFMA 16x16x32 bf16.
// ---------------------------------------------------------------------------
__global__ __launch_bounds__(256) void mfma_linear(
    const float* __restrict__ x, const unsigned short* __restrict__ Wp,
    const float* __restrict__ b, unsigned short* __restrict__ h, int M)
{
    const int lane = threadIdx.x & 63;
    const int wave = threadIdx.x >> 6;
    const int row0 = blockIdx.x * 128 + wave * 32;
    const int arow = lane & 15;
    const int kgrp = lane >> 4;

    f32x4 acc[2][16];
#pragma unroll
    for (int t = 0; t < 2; ++t)
#pragma unroll
        for (int nt = 0; nt < 16; ++nt)
            acc[t][nt] = (f32x4){0.f, 0.f, 0.f, 0.f};

    for (int kt = 0; kt < 8; ++kt) {
        const int k0 = kt * 32 + kgrp * 8;
        bf16x8 a[2];
#pragma unroll
        for (int t = 0; t < 2; ++t) {
            int r = row0 + t * 16 + arow;
            if (r >= M) r = M - 1;
            const float4* xp = (const float4*)(x + (size_t)r * D + k0);
            const float4 lo = xp[0];
            const float4 hi = xp[1];
            a[t][0] = (short)f2bf(lo.x); a[t][1] = (short)f2bf(lo.y);
            a[t][2] = (short)f2bf(lo.z); a[t][3] = (short)f2bf(lo.w);
            a[t][4] = (short)f2bf(hi.x); a[t][5] = (short)f2bf(hi.y);
            a[t][6] = (short)f2bf(hi.z); a[t][7] = (short)f2bf(hi.w);
        }
        const bf16x8* __restrict__ wp =
            (const bf16x8*)Wp + (size_t)(kt * 16) * 64 + lane;
#pragma unroll
        for (int nt = 0; nt < 16; ++nt) {
            const bf16x8 bf = wp[nt * 64];
            acc[0][nt] = __builtin_amdgcn_mfma_f32_16x16x32_bf16(a[0], bf, acc[0][nt], 0, 0, 0);
            acc[1][nt] = __builtin_amdgcn_mfma_f32_16x16x32_bf16(a[1], bf, acc[1][nt], 0, 0, 0);
        }
    }

    const int crow = (lane >> 4) * 4;
    const int ccol = lane & 15;
#pragma unroll
    for (int t = 0; t < 2; ++t)
#pragma unroll
        for (int nt = 0; nt < 16; ++nt) {
            const float bj = b[nt * 16 + ccol];
#pragma unroll
            for (int r = 0; r < 4; ++r) {
                const int row = row0 + t * 16 + crow + r;
                if (row < M)
                    h[(size_t)row * D + nt * 16 + ccol] = f2bf(acc[t][nt][r] + bj);
            }
        }
}

// ---------------------------------------------------------------------------
// CSR build: histogram -> scan -> finalize
// ---------------------------------------------------------------------------
__global__ __launch_bounds__(256) void count_rows(
    const int* __restrict__ rows, int* __restrict__ counts, int E)
{
    int i = blockIdx.x * 256 + threadIdx.x;
    const int stride = gridDim.x * 256;
    for (; i < E; i += stride) atomicAdd(&counts[rows[i]], 1);
}

__global__ __launch_bounds__(256) void scan_blocks(
    int* __restrict__ data, int* __restrict__ bsums, int n)
{
    __shared__ int wsums[4];
    const int tid = threadIdx.x;
    const int lane = tid & 63;
    const int wid = tid >> 6;
    const int base = blockIdx.x * 1024 + tid * 4;

    int c0 = 0, c1 = 0, c2 = 0, c3 = 0;
    if (base + 0 < n) c0 = data[base + 0];
    if (base + 1 < n) c1 = data[base + 1];
    if (base + 2 < n) c2 = data[base + 2];
    if (base + 3 < n) c3 = data[base + 3];
    const int tsum = c0 + c1 + c2 + c3;

    int v = tsum;
    for (int d = 1; d < 64; d <<= 1) {
        int u = __shfl_up(v, d, 64);
        if (lane >= d) v += u;
    }
    if (lane == 63) wsums[wid] = v;
    __syncthreads();

    int woff = 0;
    for (int w = 0; w < wid; ++w) woff += wsums[w];

    int run = woff + (v - tsum);
    if (base + 0 < n) data[base + 0] = run; run += c0;
    if (base + 1 < n) data[base + 1] = run; run += c1;
    if (base + 2 < n) data[base + 2] = run; run += c2;
    if (base + 3 < n) data[base + 3] = run;

    if (tid == 0) bsums[blockIdx.x] = wsums[0] + wsums[1] + wsums[2] + wsums[3];
}

__global__ void scan_bsums(int* __restrict__ bsums, int nb)
{
    if (threadIdx.x == 0 && blockIdx.x == 0) {
        int run = 0;
        for (int i = 0; i < nb; ++i) { int t = bsums[i]; bsums[i] = run; run += t; }
    }
}

// row_ptr finalize + per-bucket cursor init (bucket = BROWS rows)
__global__ __launch_bounds__(256) void finalize_rowptr(
    int* __restrict__ row_ptr, int* __restrict__ bcursor,
    const int* __restrict__ bsums, int n, int E)
{
    const int i = blockIdx.x * 256 + threadIdx.x;
    if (i < n) {
        const int v = row_ptr[i] + bsums[i >> 10];
        row_ptr[i] = v;
        if ((i & (BROWS - 1)) == 0) bcursor[i >> BSHIFT] = v;
    }
    if (i == 0) row_ptr[n] = E;
}

// ---------------------------------------------------------------------------
// Pass B: partition edges into bucket-grouped part[] (unordered in bucket).
// entry: x = (localrow << 17) | col, y = f32 val bits.
// ---------------------------------------------------------------------------
__global__ __launch_bounds__(256) void partition_edges(
    const int* __restrict__ adj_row, const int* __restrict__ adj_col,
    const float* __restrict__ adj_vals, int* __restrict__ bcursor,
    uint2* __restrict__ part, int E, int nblocks)
{
    __shared__ int hist[MAXBK];
    __shared__ int base[MAXBK];
    __shared__ int lcur[MAXBK];

    const int tid = threadIdx.x;
    const int chunk = (E + nblocks - 1) / nblocks;
    const int e0 = blockIdx.x * chunk;
    const int e1 = min(e0 + chunk, E);

    for (int k = tid; k < MAXBK; k += 256) { hist[k] = 0; lcur[k] = 0; }
    __syncthreads();

    for (int i = e0 + tid; i < e1; i += 256)
        atomicAdd(&hist[adj_row[i] >> BSHIFT], 1);
    __syncthreads();

    for (int k = tid; k < MAXBK; k += 256)
        if (hist[k] > 0) base[k] = atomicAdd(&bcursor[k], hist[k]);
    __syncthreads();

    for (int i = e0 + tid; i < e1; i += 256) {
        const int r = adj_row[i];
        const int k = r >> BSHIFT;
        const int pos = base[k] + atomicAdd(&lcur[k], 1);
        part[pos] = make_uint2(((unsigned)(r & (BROWS - 1)) << 17) | (unsigned)adj_col[i],
                               __float_as_uint(adj_vals[i]));
    }
}

// ---------------------------------------------------------------------------
// Pass C: one block per bucket; per-row cursors in LDS; csr stores confined
// to this bucket's ~130KB window (single-writer locality).
// ---------------------------------------------------------------------------
__global__ __launch_bounds__(256) void bucket_fill(
    const int* __restrict__ row_ptr, const uint2* __restrict__ part,
    int2* __restrict__ csr, int n)
{
    __shared__ int cur[BROWS];
    const int tid = threadIdx.x;
    const int row0 = blockIdx.x << BSHIFT;
    const int rend = min(row0 + BROWS, n);

    for (int r = tid; r < rend - row0; r += 256) cur[r] = row_ptr[row0 + r];
    __syncthreads();

    const int s = row_ptr[row0];
    const int e = row_ptr[rend];
    for (int i = s + tid; i < e; i += 256) {
        const uint2 w = part[i];
        const int lr = w.x >> 17;
        const int col = w.x & 0x1FFFF;
        const int pos = atomicAdd(&cur[lr], 1);
        csr[pos] = make_int2(col, (int)w.y);
    }
}

// ---------------------------------------------------------------------------
// Gather-reduce over bf16 h + fused ReLU.
// ---------------------------------------------------------------------------
__global__ __launch_bounds__(256) void gather_bf16(
    const int* __restrict__ row_ptr, const int2* __restrict__ csr,
    const unsigned short* __restrict__ h, float* __restrict__ out, int n)
{
    const int row = blockIdx.x * 4 + (threadIdx.x >> 6);
    if (row >= n) return;
    const int lane = threadIdx.x & 63;

    const int s = row_ptr[row];
    const int e = row_ptr[row + 1];

    float a0 = 0.f, a1 = 0.f, a2 = 0.f, a3 = 0.f;

    int i = s;
    for (; i + 4 <= e; i += 4) {
        const int2 c0 = csr[i + 0];
        const int2 c1 = csr[i + 1];
        const int2 c2 = csr[i + 2];
        const int2 c3 = csr[i + 3];
        const uint2 d0 = ((const uint2*)(h + (size_t)c0.x * D))[lane];
        const uint2 d1 = ((const uint2*)(h + (size_t)c1.x * D))[lane];
        const uint2 d2 = ((const uint2*)(h + (size_t)c2.x * D))[lane];
        const uint2 d3 = ((const uint2*)(h + (size_t)c3.x * D))[lane];
        const float v0 = __int_as_float(c0.y);
        const float v1 = __int_as_float(c1.y);
        const float v2 = __int_as_float(c2.y);
        const float v3 = __int_as_float(c3.y);
        a0 += v0 * bf_lo(d0.x) + v1 * bf_lo(d1.x) + v2 * bf_lo(d2.x) + v3 * bf_lo(d3.x);
        a1 += v0 * bf_hi(d0.x) + v1 * bf_hi(d1.x) + v2 * bf_hi(d2.x) + v3 * bf_hi(d3.x);
        a2 += v0 * bf_lo(d0.y) + v1 * bf_lo(d1.y) + v2 * bf_lo(d2.y) + v3 * bf_lo(d3.y);
        a3 += v0 * bf_hi(d0.y) + v1 * bf_hi(d1.y) + v2 * bf_hi(d2.y) + v3 * bf_hi(d3.y);
    }
    for (; i < e; ++i) {
        const int2 cv = csr[i];
        const uint2 dv = ((const uint2*)(h + (size_t)cv.x * D))[lane];
        const float v = __int_as_float(cv.y);
        a0 += v * bf_lo(dv.x);
        a1 += v * bf_hi(dv.x);
        a2 += v * bf_lo(dv.y);
        a3 += v * bf_hi(dv.y);
    }

    float4 st;
    st.x = fmaxf(a0, 0.f); st.y = fmaxf(a1, 0.f);
    st.z = fmaxf(a2, 0.f); st.w = fmaxf(a3, 0.f);
    ((float4*)(out + (size_t)row * D))[lane] = st;
}

// ---------------------------------------------------------------------------
extern "C" void kernel_launch(void* const* d_in, const int* in_sizes, int n_in,
                              void* d_out, int out_size, void* d_ws, size_t ws_size,
                              hipStream_t stream)
{
    const float* x        = (const float*)d_in[0];
    const int*   adj_row  = (const int*)d_in[1];
    const int*   adj_col  = (const int*)d_in[2];
    const float* adj_vals = (const float*)d_in[3];
    const float* W        = (const float*)d_in[4];
    const float* b        = (const float*)d_in[5];
    float*       out      = (float*)d_out;

    const int n = in_sizes[0] / D;          // 100000 nodes
    const int E = in_sizes[1];              // 3.2M edges
    const int NB = (n + 1023) / 1024;       // scan blocks
    const int NBK = (n + BROWS - 1) >> BSHIFT;  // buckets (196)

    char* ws = (char*)d_ws;
    size_t off = 0;
    auto alloc = [&](size_t bytes) {
        size_t o = off;
        off += (bytes + 255) & ~(size_t)255;
        return o;
    };
    unsigned short* h  = (unsigned short*)(ws + alloc((size_t)n * D * sizeof(unsigned short)));
    unsigned short* Wp = (unsigned short*)(ws + alloc((size_t)8192 * 8 * sizeof(unsigned short)));
    int*   row_ptr = (int*)  (ws + alloc((size_t)(n + 1) * sizeof(int)));
    int*   bcursor = (int*)  (ws + alloc((size_t)MAXBK * sizeof(int)));
    int*   bsums   = (int*)  (ws + alloc((size_t)NB * sizeof(int)));
    uint2* part    = (uint2*)(ws + alloc((size_t)E * sizeof(uint2)));
    int2*  csr     = (int2*) (ws + alloc((size_t)E * sizeof(int2)));
    (void)ws_size;

    // linear
    pack_W<<<32, 256, 0, stream>>>(W, Wp);
    mfma_linear<<<(n + 127) / 128, 256, 0, stream>>>(x, Wp, b, h, n);

    // CSR build (two-level partition)
    hipMemsetAsync(row_ptr, 0, (size_t)(n + 1) * sizeof(int), stream);
    count_rows<<<2048, 256, 0, stream>>>(adj_row, row_ptr, E);
    scan_blocks<<<NB, 256, 0, stream>>>(row_ptr, bsums, n);
    scan_bsums<<<1, 64, 0, stream>>>(bsums, NB);
    finalize_rowptr<<<(n + 255) / 256, 256, 0, stream>>>(row_ptr, bcursor, bsums, n, E);
    const int PBLK = 512;
    partition_edges<<<PBLK, 256, 0, stream>>>(adj_row, adj_col, adj_vals, bcursor, part, E, PBLK);
    bucket_fill<<<NBK, 256, 0, stream>>>(row_ptr, part, csr, n);

    // fused gather + ReLU
    gather_bf16<<<(n + 3) / 4, 256, 0, stream>>>(row_ptr, csr, h, out, n);
}

// Round 6
// 577.854 us; speedup vs baseline: 18.9775x; 1.0224x over previous
//
#include <hip/hip_runtime.h>

#define D 256
#define BSHIFT 9
#define BROWS 512            // rows per bucket
#define MAXBK 256            // supports n <= 131072

typedef __attribute__((ext_vector_type(8))) short bf16x8;
typedef __attribute__((ext_vector_type(4))) float f32x4;
typedef __attribute__((ext_vector_type(2))) unsigned int u32x2;

static __device__ __forceinline__ unsigned short f2bf(float f) {
    unsigned u = __float_as_uint(f);
    u += 0x7FFF + ((u >> 16) & 1);   // round-to-nearest-even
    return (unsigned short)(u >> 16);
}
static __device__ __forceinline__ float bf_lo(unsigned u) {
    return __uint_as_float(u << 16);
}
static __device__ __forceinline__ float bf_hi(unsigned u) {
    return __uint_as_float(u & 0xFFFF0000u);
}

// ---------------------------------------------------------------------------
// pack W (f32 [256][256]) into MFMA-B fragment order, bf16.
// ---------------------------------------------------------------------------
__global__ __launch_bounds__(256) void pack_W(
    const float* __restrict__ W, unsigned short* __restrict__ Wp)
{
    const int t = blockIdx.x * 256 + threadIdx.x;   // 0..8191
    const int lane = t & 63;
    const int nt = (t >> 6) & 15;
    const int kt = t >> 10;
    const int n = nt * 16 + (lane & 15);
    const int k0 = kt * 32 + (lane >> 4) * 8;
#pragma unroll
    for (int j = 0; j < 8; ++j)
        Wp[(size_t)t * 8 + j] = f2bf(W[n * D + k0 + j]);
}

// ---------------------------------------------------------------------------
// h = bf16(x @ W^T + b) via MFMA 16x16x32 bf16.
// x loads are non-temporal (single-use stream; keep L3 for h).
// ---------------------------------------------------------------------------
__global__ __launch_bounds__(256) void mfma_linear(
    const float* __restrict__ x, const unsigned short* __restrict__ Wp,
    const float* __restrict__ b, unsigned short* __restrict__ h, int M)
{
    const int lane = threadIdx.x & 63;
    const int wave = threadIdx.x >> 6;
    const int row0 = blockIdx.x * 128 + wave * 32;
    const int arow = lane & 15;
    const int kgrp = lane >> 4;

    f32x4 acc[2][16];
#pragma unroll
    for (int t = 0; t < 2; ++t)
#pragma unroll
        for (int nt = 0; nt < 16; ++nt)
            acc[t][nt] = (f32x4){0.f, 0.f, 0.f, 0.f};

    for (int kt = 0; kt < 8; ++kt) {
        const int k0 = kt * 32 + kgrp * 8;
        bf16x8 a[2];
#pragma unroll
        for (int t = 0; t < 2; ++t) {
            int r = row0 + t * 16 + arow;
            if (r >= M) r = M - 1;
            const f32x4* xp = (const f32x4*)(x + (size_t)r * D + k0);
            const f32x4 lo = __builtin_nontemporal_load(xp);
            const f32x4 hi = __builtin_nontemporal_load(xp + 1);
            a[t][0] = (short)f2bf(lo[0]); a[t][1] = (short)f2bf(lo[1]);
            a[t][2] = (short)f2bf(lo[2]); a[t][3] = (short)f2bf(lo[3]);
            a[t][4] = (short)f2bf(hi[0]); a[t][5] = (short)f2bf(hi[1]);
            a[t][6] = (short)f2bf(hi[2]); a[t][7] = (short)f2bf(hi[3]);
        }
        const bf16x8* __restrict__ wp =
            (const bf16x8*)Wp + (size_t)(kt * 16) * 64 + lane;
#pragma unroll
        for (int nt = 0; nt < 16; ++nt) {
            const bf16x8 bf = wp[nt * 64];
            acc[0][nt] = __builtin_amdgcn_mfma_f32_16x16x32_bf16(a[0], bf, acc[0][nt], 0, 0, 0);
            acc[1][nt] = __builtin_amdgcn_mfma_f32_16x16x32_bf16(a[1], bf, acc[1][nt], 0, 0, 0);
        }
    }

    const int crow = (lane >> 4) * 4;
    const int ccol = lane & 15;
#pragma unroll
    for (int t = 0; t < 2; ++t)
#pragma unroll
        for (int nt = 0; nt < 16; ++nt) {
            const float bj = b[nt * 16 + ccol];
#pragma unroll
            for (int r = 0; r < 4; ++r) {
                const int row = row0 + t * 16 + crow + r;
                if (row < M)
                    h[(size_t)row * D + nt * 16 + ccol] = f2bf(acc[t][nt][r] + bj);
            }
        }
}

// ---------------------------------------------------------------------------
// CSR build: histogram -> scan -> finalize
// ---------------------------------------------------------------------------
__global__ __launch_bounds__(256) void count_rows(
    const int* __restrict__ rows, int* __restrict__ counts, int E)
{
    int i = blockIdx.x * 256 + threadIdx.x;
    const int stride = gridDim.x * 256;
    for (; i < E; i += stride) atomicAdd(&counts[rows[i]], 1);
}

__global__ __launch_bounds__(256) void scan_blocks(
    int* __restrict__ data, int* __restrict__ bsums, int n)
{
    __shared__ int wsums[4];
    const int tid = threadIdx.x;
    const int lane = tid & 63;
    const int wid = tid >> 6;
    const int base = blockIdx.x * 1024 + tid * 4;

    int c0 = 0, c1 = 0, c2 = 0, c3 = 0;
    if (base + 0 < n) c0 = data[base + 0];
    if (base + 1 < n) c1 = data[base + 1];
    if (base + 2 < n) c2 = data[base + 2];
    if (base + 3 < n) c3 = data[base + 3];
    const int tsum = c0 + c1 + c2 + c3;

    int v = tsum;
    for (int d = 1; d < 64; d <<= 1) {
        int u = __shfl_up(v, d, 64);
        if (lane >= d) v += u;
    }
    if (lane == 63) wsums[wid] = v;
    __syncthreads();

    int woff = 0;
    for (int w = 0; w < wid; ++w) woff += wsums[w];

    int run = woff + (v - tsum);
    if (base + 0 < n) data[base + 0] = run; run += c0;
    if (base + 1 < n) data[base + 1] = run; run += c1;
    if (base + 2 < n) data[base + 2] = run; run += c2;
    if (base + 3 < n) data[base + 3] = run;

    if (tid == 0) bsums[blockIdx.x] = wsums[0] + wsums[1] + wsums[2] + wsums[3];
}

__global__ void scan_bsums(int* __restrict__ bsums, int nb)
{
    if (threadIdx.x == 0 && blockIdx.x == 0) {
        int run = 0;
        for (int i = 0; i < nb; ++i) { int t = bsums[i]; bsums[i] = run; run += t; }
    }
}

// row_ptr finalize + per-bucket cursor init (bucket = BROWS rows)
__global__ __launch_bounds__(256) void finalize_rowptr(
    int* __restrict__ row_ptr, int* __restrict__ bcursor,
    const int* __restrict__ bsums, int n, int E)
{
    const int i = blockIdx.x * 256 + threadIdx.x;
    if (i < n) {
        const int v = row_ptr[i] + bsums[i >> 10];
        row_ptr[i] = v;
        if ((i & (BROWS - 1)) == 0) bcursor[i >> BSHIFT] = v;
    }
    if (i == 0) row_ptr[n] = E;
}

// ---------------------------------------------------------------------------
// Pass B: partition edges into bucket-grouped part[].
// col/vals loads non-temporal (single-use).
// ---------------------------------------------------------------------------
__global__ __launch_bounds__(256) void partition_edges(
    const int* __restrict__ adj_row, const int* __restrict__ adj_col,
    const float* __restrict__ adj_vals, int* __restrict__ bcursor,
    uint2* __restrict__ part, int E, int nblocks)
{
    __shared__ int hist[MAXBK];
    __shared__ int base[MAXBK];
    __shared__ int lcur[MAXBK];

    const int tid = threadIdx.x;
    const int chunk = (E + nblocks - 1) / nblocks;
    const int e0 = blockIdx.x * chunk;
    const int e1 = min(e0 + chunk, E);

    for (int k = tid; k < MAXBK; k += 256) { hist[k] = 0; lcur[k] = 0; }
    __syncthreads();

    for (int i = e0 + tid; i < e1; i += 256)
        atomicAdd(&hist[adj_row[i] >> BSHIFT], 1);
    __syncthreads();

    for (int k = tid; k < MAXBK; k += 256)
        if (hist[k] > 0) base[k] = atomicAdd(&bcursor[k], hist[k]);
    __syncthreads();

    for (int i = e0 + tid; i < e1; i += 256) {
        const int r = adj_row[i];
        const int k = r >> BSHIFT;
        const int col = __builtin_nontemporal_load(adj_col + i);
        const float val = __builtin_nontemporal_load(adj_vals + i);
        const int pos = base[k] + atomicAdd(&lcur[k], 1);
        part[pos] = make_uint2(((unsigned)(r & (BROWS - 1)) << 17) | (unsigned)col,
                               __float_as_uint(val));
    }
}

// ---------------------------------------------------------------------------
// Pass C: one block per bucket; per-row cursors in LDS; csr stores confined
// to this bucket's ~130KB window.
// ---------------------------------------------------------------------------
__global__ __launch_bounds__(256) void bucket_fill(
    const int* __restrict__ row_ptr, const uint2* __restrict__ part,
    int2* __restrict__ csr, int n)
{
    __shared__ int cur[BROWS];
    const int tid = threadIdx.x;
    const int row0 = blockIdx.x << BSHIFT;
    const int rend = min(row0 + BROWS, n);

    for (int r = tid; r < rend - row0; r += 256) cur[r] = row_ptr[row0 + r];
    __syncthreads();

    const int s = row_ptr[row0];
    const int e = row_ptr[rend];
    for (int i = s + tid; i < e; i += 256) {
        const uint2 w = part[i];
        const int lr = w.x >> 17;
        const int col = w.x & 0x1FFFF;
        const int pos = atomicAdd(&cur[lr], 1);
        csr[pos] = make_int2(col, (int)w.y);
    }
}

// ---------------------------------------------------------------------------
// Gather-reduce over bf16 h + fused ReLU. out stores NON-TEMPORAL so the
// 102 MB output stream doesn't evict h (51 MB) from the 256 MB L3.
// ---------------------------------------------------------------------------
__global__ __launch_bounds__(256) void gather_bf16(
    const int* __restrict__ row_ptr, const int2* __restrict__ csr,
    const unsigned short* __restrict__ h, float* __restrict__ out, int n)
{
    const int row = blockIdx.x * 4 + (threadIdx.x >> 6);
    if (row >= n) return;
    const int lane = threadIdx.x & 63;

    const int s = row_ptr[row];
    const int e = row_ptr[row + 1];

    float a0 = 0.f, a1 = 0.f, a2 = 0.f, a3 = 0.f;

    int i = s;
    for (; i + 4 <= e; i += 4) {
        const int2 c0 = csr[i + 0];
        const int2 c1 = csr[i + 1];
        const int2 c2 = csr[i + 2];
        const int2 c3 = csr[i + 3];
        const uint2 d0 = ((const uint2*)(h + (size_t)c0.x * D))[lane];
        const uint2 d1 = ((const uint2*)(h + (size_t)c1.x * D))[lane];
        const uint2 d2 = ((const uint2*)(h + (size_t)c2.x * D))[lane];
        const uint2 d3 = ((const uint2*)(h + (size_t)c3.x * D))[lane];
        const float v0 = __int_as_float(c0.y);
        const float v1 = __int_as_float(c1.y);
        const float v2 = __int_as_float(c2.y);
        const float v3 = __int_as_float(c3.y);
        a0 += v0 * bf_lo(d0.x) + v1 * bf_lo(d1.x) + v2 * bf_lo(d2.x) + v3 * bf_lo(d3.x);
        a1 += v0 * bf_hi(d0.x) + v1 * bf_hi(d1.x) + v2 * bf_hi(d2.x) + v3 * bf_hi(d3.x);
        a2 += v0 * bf_lo(d0.y) + v1 * bf_lo(d1.y) + v2 * bf_lo(d2.y) + v3 * bf_lo(d3.y);
        a3 += v0 * bf_hi(d0.y) + v1 * bf_hi(d1.y) + v2 * bf_hi(d2.y) + v3 * bf_hi(d3.y);
    }
    for (; i < e; ++i) {
        const int2 cv = csr[i];
        const uint2 dv = ((const uint2*)(h + (size_t)cv.x * D))[lane];
        const float v = __int_as_float(cv.y);
        a0 += v * bf_lo(dv.x);
        a1 += v * bf_hi(dv.x);
        a2 += v * bf_lo(dv.y);
        a3 += v * bf_hi(dv.y);
    }

    f32x4 st;
    st[0] = fmaxf(a0, 0.f); st[1] = fmaxf(a1, 0.f);
    st[2] = fmaxf(a2, 0.f); st[3] = fmaxf(a3, 0.f);
    __builtin_nontemporal_store(st, (f32x4*)(out + (size_t)row * D) + lane);
}

// ---------------------------------------------------------------------------
extern "C" void kernel_launch(void* const* d_in, const int* in_sizes, int n_in,
                              void* d_out, int out_size, void* d_ws, size_t ws_size,
                              hipStream_t stream)
{
    const float* x        = (const float*)d_in[0];
    const int*   adj_row  = (const int*)d_in[1];
    const int*   adj_col  = (const int*)d_in[2];
    const float* adj_vals = (const float*)d_in[3];
    const float* W        = (const float*)d_in[4];
    const float* b        = (const float*)d_in[5];
    float*       out      = (float*)d_out;

    const int n = in_sizes[0] / D;          // 100000 nodes
    const int E = in_sizes[1];              // 3.2M edges
    const int NB = (n + 1023) / 1024;       // scan blocks
    const int NBK = (n + BROWS - 1) >> BSHIFT;  // buckets (196)

    char* ws = (char*)d_ws;
    size_t off = 0;
    auto alloc = [&](size_t bytes) {
        size_t o = off;
        off += (bytes + 255) & ~(size_t)255;
        return o;
    };
    unsigned short* h  = (unsigned short*)(ws + alloc((size_t)n * D * sizeof(unsigned short)));
    unsigned short* Wp = (unsigned short*)(ws + alloc((size_t)8192 * 8 * sizeof(unsigned short)));
    int*   row_ptr = (int*)  (ws + alloc((size_t)(n + 1) * sizeof(int)));
    int*   bcursor = (int*)  (ws + alloc((size_t)MAXBK * sizeof(int)));
    int*   bsums   = (int*)  (ws + alloc((size_t)NB * sizeof(int)));
    uint2* part    = (uint2*)(ws + alloc((size_t)E * sizeof(uint2)));
    int2*  csr     = (int2*) (ws + alloc((size_t)E * sizeof(int2)));
    (void)ws_size;

    // linear
    pack_W<<<32, 256, 0, stream>>>(W, Wp);
    mfma_linear<<<(n + 127) / 128, 256, 0, stream>>>(x, Wp, b, h, n);

    // CSR build (two-level partition)
    hipMemsetAsync(row_ptr, 0, (size_t)(n + 1) * sizeof(int), stream);
    count_rows<<<2048, 256, 0, stream>>>(adj_row, row_ptr, E);
    scan_blocks<<<NB, 256, 0, stream>>>(row_ptr, bsums, n);
    scan_bsums<<<1, 64, 0, stream>>>(bsums, NB);
    finalize_rowptr<<<(n + 255) / 256, 256, 0, stream>>>(row_ptr, bcursor, bsums, n, E);
    const int PBLK = 512;
    partition_edges<<<PBLK, 256, 0, stream>>>(adj_row, adj_col, adj_vals, bcursor, part, E, PBLK);
    bucket_fill<<<NBK, 256, 0, stream>>>(row_ptr, part, csr, n);

    // fused gather + ReLU
    gather_bf16<<<(n + 3) / 4, 256, 0, stream>>>(row_ptr, csr, h, out, n);
}

// Round 7
// 466.042 us; speedup vs baseline: 23.5305x; 1.2399x over previous
//
#include <hip/hip_runtime.h>

#define D 256
#define BSHIFT 9
#define BROWS 512            // rows per bucket
#define MAXBK 256            // supports n <= 131072
#define PBLK 512             // partition blocks

typedef __attribute__((ext_vector_type(8))) short bf16x8;
typedef __attribute__((ext_vector_type(4))) float f32x4;

static __device__ __forceinline__ unsigned short f2bf(float f) {
    unsigned u = __float_as_uint(f);
    u += 0x7FFF + ((u >> 16) & 1);   // round-to-nearest-even
    return (unsigned short)(u >> 16);
}
static __device__ __forceinline__ float bf_lo(unsigned u) {
    return __uint_as_float(u << 16);
}
static __device__ __forceinline__ float bf_hi(unsigned u) {
    return __uint_as_float(u & 0xFFFF0000u);
}

// ---------------------------------------------------------------------------
// pack W (f32 [256][256]) into MFMA-B fragment order, bf16.
// ---------------------------------------------------------------------------
__global__ __launch_bounds__(256) void pack_W(
    const float* __restrict__ W, unsigned short* __restrict__ Wp)
{
    const int t = blockIdx.x * 256 + threadIdx.x;   // 0..8191
    const int lane = t & 63;
    const int nt = (t >> 6) & 15;
    const int kt = t >> 10;
    const int n = nt * 16 + (lane & 15);
    const int k0 = kt * 32 + (lane >> 4) * 8;
#pragma unroll
    for (int j = 0; j < 8; ++j)
        Wp[(size_t)t * 8 + j] = f2bf(W[n * D + k0 + j]);
}

// ---------------------------------------------------------------------------
// h = bf16(x @ W^T + b) via MFMA 16x16x32 bf16.
// ---------------------------------------------------------------------------
__global__ __launch_bounds__(256) void mfma_linear(
    const float* __restrict__ x, const unsigned short* __restrict__ Wp,
    const float* __restrict__ b, unsigned short* __restrict__ h, int M)
{
    const int lane = threadIdx.x & 63;
    const int wave = threadIdx.x >> 6;
    const int row0 = blockIdx.x * 128 + wave * 32;
    const int arow = lane & 15;
    const int kgrp = lane >> 4;

    f32x4 acc[2][16];
#pragma unroll
    for (int t = 0; t < 2; ++t)
#pragma unroll
        for (int nt = 0; nt < 16; ++nt)
            acc[t][nt] = (f32x4){0.f, 0.f, 0.f, 0.f};

    for (int kt = 0; kt < 8; ++kt) {
        const int k0 = kt * 32 + kgrp * 8;
        bf16x8 a[2];
#pragma unroll
        for (int t = 0; t < 2; ++t) {
            int r = row0 + t * 16 + arow;
            if (r >= M) r = M - 1;
            const f32x4* xp = (const f32x4*)(x + (size_t)r * D + k0);
            const f32x4 lo = __builtin_nontemporal_load(xp);
            const f32x4 hi = __builtin_nontemporal_load(xp + 1);
            a[t][0] = (short)f2bf(lo[0]); a[t][1] = (short)f2bf(lo[1]);
            a[t][2] = (short)f2bf(lo[2]); a[t][3] = (short)f2bf(lo[3]);
            a[t][4] = (short)f2bf(hi[0]); a[t][5] = (short)f2bf(hi[1]);
            a[t][6] = (short)f2bf(hi[2]); a[t][7] = (short)f2bf(hi[3]);
        }
        const bf16x8* __restrict__ wp =
            (const bf16x8*)Wp + (size_t)(kt * 16) * 64 + lane;
#pragma unroll
        for (int nt = 0; nt < 16; ++nt) {
            const bf16x8 bf = wp[nt * 64];
            acc[0][nt] = __builtin_amdgcn_mfma_f32_16x16x32_bf16(a[0], bf, acc[0][nt], 0, 0, 0);
            acc[1][nt] = __builtin_amdgcn_mfma_f32_16x16x32_bf16(a[1], bf, acc[1][nt], 0, 0, 0);
        }
    }

    const int crow = (lane >> 4) * 4;
    const int ccol = lane & 15;
#pragma unroll
    for (int t = 0; t < 2; ++t)
#pragma unroll
        for (int nt = 0; nt < 16; ++nt) {
            const float bj = b[nt * 16 + ccol];
#pragma unroll
            for (int r = 0; r < 4; ++r) {
                const int row = row0 + t * 16 + crow + r;
                if (row < M)
                    h[(size_t)row * D + nt * 16 + ccol] = f2bf(acc[t][nt][r] + bj);
            }
        }
}

// ---------------------------------------------------------------------------
// K3: per-block bucket histogram (LDS only, no global atomics).
// blk_hist layout: [blk][bucket].
// ---------------------------------------------------------------------------
__global__ __launch_bounds__(256) void bucket_count(
    const int* __restrict__ adj_row, int* __restrict__ blk_hist, int E, int nbk)
{
    __shared__ int hist[MAXBK];
    const int tid = threadIdx.x;
    const int chunk = (E + PBLK - 1) / PBLK;
    const int e0 = blockIdx.x * chunk;
    const int e1 = min(e0 + chunk, E);

    for (int k = tid; k < nbk; k += 256) hist[k] = 0;
    __syncthreads();
    for (int i = e0 + tid; i < e1; i += 256)
        atomicAdd(&hist[adj_row[i] >> BSHIFT], 1);
    __syncthreads();
    for (int k = tid; k < nbk; k += 256)
        blk_hist[(size_t)blockIdx.x * nbk + k] = hist[k];
}

// ---------------------------------------------------------------------------
// K4: for each bucket k, exclusive-scan blk_hist[0..PBLK-1][k] in place;
// cnt[k] = total. One block (256 thr) per bucket; pair-scan of 512 values.
// ---------------------------------------------------------------------------
__global__ __launch_bounds__(256) void scan_blk_hist(
    int* __restrict__ blk_hist, int* __restrict__ cnt, int nbk)
{
    __shared__ int wsums[4];
    const int k = blockIdx.x;
    const int tid = threadIdx.x;
    const int lane = tid & 63;
    const int wid = tid >> 6;

    const int i0 = 2 * tid, i1 = 2 * tid + 1;
    const int h0 = blk_hist[(size_t)i0 * nbk + k];
    const int h1 = blk_hist[(size_t)i1 * nbk + k];
    const int tsum = h0 + h1;

    int v = tsum;
    for (int d = 1; d < 64; d <<= 1) {
        int u = __shfl_up(v, d, 64);
        if (lane >= d) v += u;
    }
    if (lane == 63) wsums[wid] = v;
    __syncthreads();
    int woff = 0;
    for (int w = 0; w < wid; ++w) woff += wsums[w];
    const int pref = woff + v - tsum;   // exclusive prefix for this pair

    blk_hist[(size_t)i0 * nbk + k] = pref;
    blk_hist[(size_t)i1 * nbk + k] = pref + h0;
    if (tid == 0) cnt[k] = wsums[0] + wsums[1] + wsums[2] + wsums[3];
}

// ---------------------------------------------------------------------------
// K5: exclusive scan of cnt[0..nbk-1] -> bbase. Single block, nbk <= 256.
// ---------------------------------------------------------------------------
__global__ __launch_bounds__(256) void scan_cnt(
    const int* __restrict__ cnt, int* __restrict__ bbase, int nbk)
{
    __shared__ int wsums[4];
    const int tid = threadIdx.x;
    const int lane = tid & 63;
    const int wid = tid >> 6;
    const int val = (tid < nbk) ? cnt[tid] : 0;

    int v = val;
    for (int d = 1; d < 64; d <<= 1) {
        int u = __shfl_up(v, d, 64);
        if (lane >= d) v += u;
    }
    if (lane == 63) wsums[wid] = v;
    __syncthreads();
    int woff = 0;
    for (int w = 0; w < wid; ++w) woff += wsums[w];
    if (tid < nbk) bbase[tid] = woff + v - val;
}

// ---------------------------------------------------------------------------
// K6: partition edges into bucket-grouped part[] using precomputed bases
// (no global atomics; LDS cursor for within-block packing).
// entry: x = (localrow << 17) | col, y = f32 val bits.
// ---------------------------------------------------------------------------
__global__ __launch_bounds__(256) void partition_edges(
    const int* __restrict__ adj_row, const int* __restrict__ adj_col,
    const float* __restrict__ adj_vals, const int* __restrict__ bbase,
    const int* __restrict__ blk_hist, uint2* __restrict__ part, int E, int nbk)
{
    __shared__ int sbase[MAXBK];
    __shared__ int lcur[MAXBK];

    const int tid = threadIdx.x;
    const int blk = blockIdx.x;
    const int chunk = (E + PBLK - 1) / PBLK;
    const int e0 = blk * chunk;
    const int e1 = min(e0 + chunk, E);

    for (int k = tid; k < nbk; k += 256) {
        sbase[k] = bbase[k] + blk_hist[(size_t)blk * nbk + k];
        lcur[k] = 0;
    }
    __syncthreads();

    for (int i = e0 + tid; i < e1; i += 256) {
        const int r = adj_row[i];
        const int k = r >> BSHIFT;
        const int col = __builtin_nontemporal_load(adj_col + i);
        const float val = __builtin_nontemporal_load(adj_vals + i);
        const int pos = sbase[k] + atomicAdd(&lcur[k], 1);
        part[pos] = make_uint2(((unsigned)(r & (BROWS - 1)) << 17) | (unsigned)col,
                               __float_as_uint(val));
    }
}

// ---------------------------------------------------------------------------
// K7: one block per bucket. Pass 1: local row histogram + in-LDS scan ->
// row_ptr for this bucket. Pass 2: scatter part -> csr via LDS cursors.
// ---------------------------------------------------------------------------
__global__ __launch_bounds__(256) void bucket_fill(
    const uint2* __restrict__ part, const int* __restrict__ bbase,
    int* __restrict__ row_ptr, int2* __restrict__ csr, int n, int E, int nbk)
{
    __shared__ int hist[BROWS];
    __shared__ int off[BROWS];
    __shared__ int wsums[4];

    const int tid = threadIdx.x;
    const int lane = tid & 63;
    const int wid = tid >> 6;
    const int bk = blockIdx.x;
    const int row0 = bk << BSHIFT;
    const int nr = min(row0 + BROWS, n) - row0;
    const int base = bbase[bk];
    const int ecnt = ((bk + 1 < nbk) ? bbase[bk + 1] : E) - base;

    for (int r = tid; r < BROWS; r += 256) hist[r] = 0;
    __syncthreads();
    for (int i = tid; i < ecnt; i += 256)
        atomicAdd(&hist[part[base + i].x >> 17], 1);
    __syncthreads();

    // pair-scan of 512 LDS values
    const int h0 = hist[2 * tid], h1 = hist[2 * tid + 1];
    const int tsum = h0 + h1;
    int v = tsum;
    for (int d = 1; d < 64; d <<= 1) {
        int u = __shfl_up(v, d, 64);
        if (lane >= d) v += u;
    }
    if (lane == 63) wsums[wid] = v;
    __syncthreads();
    int woff = 0;
    for (int w = 0; w < wid; ++w) woff += wsums[w];
    const int pref = woff + v - tsum;
    off[2 * tid] = pref;
    off[2 * tid + 1] = pref + h0;
    __syncthreads();

    // write row_ptr (global positions) + cursors
    for (int r = tid; r < nr; r += 256) row_ptr[row0 + r] = base + off[r];
    if (bk == nbk - 1 && tid == 0) row_ptr[n] = E;
    for (int r = tid; r < BROWS; r += 256) hist[r] = base + off[r];
    __syncthreads();

    for (int i = tid; i < ecnt; i += 256) {
        const uint2 w = part[base + i];
        const int lr = w.x >> 17;
        const int pos = atomicAdd(&hist[lr], 1);
        csr[pos] = make_int2((int)(w.x & 0x1FFFF), (int)w.y);
    }
}

// ---------------------------------------------------------------------------
// K8/K9: gather over one col-half (128 cols) of bf16 h + fused ReLU.
// One wave per row; lanes 0-31 process even-slot edges, 32-63 odd-slot;
// shfl_xor(32) combine at the end. Launched twice (c0 = 0, 128) so the hot
// h slice per launch is 25.6 MB (L3-resident under the out write stream).
// ---------------------------------------------------------------------------
__global__ __launch_bounds__(256) void gather_half(
    const int* __restrict__ row_ptr, const int2* __restrict__ csr,
    const unsigned short* __restrict__ h, float* __restrict__ out, int n, int c0)
{
    const int row = blockIdx.x * 4 + (threadIdx.x >> 6);
    if (row >= n) return;
    const int lane = threadIdx.x & 63;
    const int half = lane >> 5;
    const int l32 = lane & 31;

    const int s = row_ptr[row];
    const int e = row_ptr[row + 1];

    float a0 = 0.f, a1 = 0.f, a2 = 0.f, a3 = 0.f;

    for (int i = s; i < e; i += 4) {
        const int idx0 = i + half;
        const int idx1 = i + 2 + half;
        const bool v0ok = idx0 < e;
        const bool v1ok = idx1 < e;
        const int2 cv0 = csr[v0ok ? idx0 : s];
        const int2 cv1 = csr[v1ok ? idx1 : s];
        const float v0 = v0ok ? __int_as_float(cv0.y) : 0.f;
        const float v1 = v1ok ? __int_as_float(cv1.y) : 0.f;
        const uint2 d0 = ((const uint2*)(h + (size_t)cv0.x * D + c0))[l32];
        const uint2 d1 = ((const uint2*)(h + (size_t)cv1.x * D + c0))[l32];
        a0 += v0 * bf_lo(d0.x) + v1 * bf_lo(d1.x);
        a1 += v0 * bf_hi(d0.x) + v1 * bf_hi(d1.x);
        a2 += v0 * bf_lo(d0.y) + v1 * bf_lo(d1.y);
        a3 += v0 * bf_hi(d0.y) + v1 * bf_hi(d1.y);
    }

    // combine the two edge-halves
    a0 += __shfl_xor(a0, 32, 64);
    a1 += __shfl_xor(a1, 32, 64);
    a2 += __shfl_xor(a2, 32, 64);
    a3 += __shfl_xor(a3, 32, 64);

    if (half == 0) {
        f32x4 st;
        st[0] = fmaxf(a0, 0.f); st[1] = fmaxf(a1, 0.f);
        st[2] = fmaxf(a2, 0.f); st[3] = fmaxf(a3, 0.f);
        __builtin_nontemporal_store(st, (f32x4*)(out + (size_t)row * D + c0) + l32);
    }
}

// ---------------------------------------------------------------------------
extern "C" void kernel_launch(void* const* d_in, const int* in_sizes, int n_in,
                              void* d_out, int out_size, void* d_ws, size_t ws_size,
                              hipStream_t stream)
{
    const float* x        = (const float*)d_in[0];
    const int*   adj_row  = (const int*)d_in[1];
    const int*   adj_col  = (const int*)d_in[2];
    const float* adj_vals = (const float*)d_in[3];
    const float* W        = (const float*)d_in[4];
    const float* b        = (const float*)d_in[5];
    float*       out      = (float*)d_out;

    const int n = in_sizes[0] / D;               // 100000 nodes
    const int E = in_sizes[1];                   // 3.2M edges
    const int nbk = (n + BROWS - 1) >> BSHIFT;   // buckets (196)

    char* ws = (char*)d_ws;
    size_t off = 0;
    auto alloc = [&](size_t bytes) {
        size_t o = off;
        off += (bytes + 255) & ~(size_t)255;
        return o;
    };
    unsigned short* h  = (unsigned short*)(ws + alloc((size_t)n * D * sizeof(unsigned short)));
    unsigned short* Wp = (unsigned short*)(ws + alloc((size_t)8192 * 8 * sizeof(unsigned short)));
    int*   blk_hist = (int*)  (ws + alloc((size_t)PBLK * nbk * sizeof(int)));
    int*   cnt      = (int*)  (ws + alloc((size_t)MAXBK * sizeof(int)));
    int*   bbase    = (int*)  (ws + alloc((size_t)MAXBK * sizeof(int)));
    int*   row_ptr  = (int*)  (ws + alloc((size_t)(n + 1) * sizeof(int)));
    uint2* part     = (uint2*)(ws + alloc((size_t)E * sizeof(uint2)));
    int2*  csr      = (int2*) (ws + alloc((size_t)E * sizeof(int2)));
    (void)ws_size;

    // linear
    pack_W<<<32, 256, 0, stream>>>(W, Wp);
    mfma_linear<<<(n + 127) / 128, 256, 0, stream>>>(x, Wp, b, h, n);

    // CSR build — atomic-free (LDS histograms + deterministic scans)
    bucket_count<<<PBLK, 256, 0, stream>>>(adj_row, blk_hist, E, nbk);
    scan_blk_hist<<<nbk, 256, 0, stream>>>(blk_hist, cnt, nbk);
    scan_cnt<<<1, 256, 0, stream>>>(cnt, bbase, nbk);
    partition_edges<<<PBLK, 256, 0, stream>>>(adj_row, adj_col, adj_vals, bbase, blk_hist, part, E, nbk);
    bucket_fill<<<nbk, 256, 0, stream>>>(part, bbase, row_ptr, csr, n, E, nbk);

    // fused gather + ReLU, two sequential col-half passes for L3 residency
    gather_half<<<(n + 3) / 4, 256, 0, stream>>>(row_ptr, csr, h, out, n, 0);
    gather_half<<<(n + 3) / 4, 256, 0, stream>>>(row_ptr, csr, h, out, n, 128);
}

// Round 8
// 422.100 us; speedup vs baseline: 25.9802x; 1.1041x over previous
//
#include <hip/hip_runtime.h>

#define D 256
#define BSHIFT 9
#define BROWS 512            // rows per bucket
#define MAXBK 256            // supports n <= 131072
#define PBLK 512             // partition blocks

typedef __attribute__((ext_vector_type(8))) short bf16x8;
typedef __attribute__((ext_vector_type(4))) float f32x4;
typedef __attribute__((ext_vector_type(4))) unsigned short u16x4;

static __device__ __forceinline__ unsigned short f2bf(float f) {
    unsigned u = __float_as_uint(f);
    u += 0x7FFF + ((u >> 16) & 1);   // round-to-nearest-even
    return (unsigned short)(u >> 16);
}
static __device__ __forceinline__ float bf_lo(unsigned u) {
    return __uint_as_float(u << 16);
}
static __device__ __forceinline__ float bf_hi(unsigned u) {
    return __uint_as_float(u & 0xFFFF0000u);
}

// ---------------------------------------------------------------------------
// pack W (f32 [256][256]) into MFMA fragment order, bf16.
// Lane holds W[n=lane&15][k = kt*32+(lane>>4)*8+j] for tile t=(kt*16+nt)*64.
// Used as the A operand: A[m][k], m = wcol.
// ---------------------------------------------------------------------------
__global__ __launch_bounds__(256) void pack_W(
    const float* __restrict__ W, unsigned short* __restrict__ Wp)
{
    const int t = blockIdx.x * 256 + threadIdx.x;   // 0..8191
    const int lane = t & 63;
    const int nt = (t >> 6) & 15;
    const int kt = t >> 10;
    const int n = nt * 16 + (lane & 15);
    const int k0 = kt * 32 + (lane >> 4) * 8;
#pragma unroll
    for (int j = 0; j < 8; ++j)
        Wp[(size_t)t * 8 + j] = f2bf(W[n * D + k0 + j]);
}

// ---------------------------------------------------------------------------
// h = bf16(x @ W^T + b) via MFMA 16x16x32 bf16, SWAPPED operands:
// D = mfma(W_frag, x_frag) = h^T-tile => lane holds 4 CONSECUTIVE h-cols
// for one x-row => packed ushort4 (8B) stores instead of 128x 2B stores.
// ---------------------------------------------------------------------------
__global__ __launch_bounds__(256) void mfma_linear(
    const float* __restrict__ x, const unsigned short* __restrict__ Wp,
    const float* __restrict__ b, unsigned short* __restrict__ h, int M)
{
    const int lane = threadIdx.x & 63;
    const int wave = threadIdx.x >> 6;
    const int row0 = blockIdx.x * 128 + wave * 32;
    const int arow = lane & 15;
    const int kgrp = lane >> 4;

    f32x4 acc[2][16];
#pragma unroll
    for (int t = 0; t < 2; ++t)
#pragma unroll
        for (int nt = 0; nt < 16; ++nt)
            acc[t][nt] = (f32x4){0.f, 0.f, 0.f, 0.f};

    for (int kt = 0; kt < 8; ++kt) {
        const int k0 = kt * 32 + kgrp * 8;
        bf16x8 a[2];
#pragma unroll
        for (int t = 0; t < 2; ++t) {
            int r = row0 + t * 16 + arow;
            if (r >= M) r = M - 1;
            const f32x4* xp = (const f32x4*)(x + (size_t)r * D + k0);
            const f32x4 lo = __builtin_nontemporal_load(xp);
            const f32x4 hi = __builtin_nontemporal_load(xp + 1);
            a[t][0] = (short)f2bf(lo[0]); a[t][1] = (short)f2bf(lo[1]);
            a[t][2] = (short)f2bf(lo[2]); a[t][3] = (short)f2bf(lo[3]);
            a[t][4] = (short)f2bf(hi[0]); a[t][5] = (short)f2bf(hi[1]);
            a[t][6] = (short)f2bf(hi[2]); a[t][7] = (short)f2bf(hi[3]);
        }
        const bf16x8* __restrict__ wp =
            (const bf16x8*)Wp + (size_t)(kt * 16) * 64 + lane;
#pragma unroll
        for (int nt = 0; nt < 16; ++nt) {
            const bf16x8 bf = wp[nt * 64];
            // swapped: A = W frag, B = x frag  =>  D[wcol][xrow]
            acc[0][nt] = __builtin_amdgcn_mfma_f32_16x16x32_bf16(bf, a[0], acc[0][nt], 0, 0, 0);
            acc[1][nt] = __builtin_amdgcn_mfma_f32_16x16x32_bf16(bf, a[1], acc[1][nt], 0, 0, 0);
        }
    }

    // D layout (swapped): xrow = lane&15, wcol = nt*16 + (lane>>4)*4 + reg
    const int srow = lane & 15;
    const int scol0 = (lane >> 4) * 4;
#pragma unroll
    for (int t = 0; t < 2; ++t) {
        const int xrow = row0 + t * 16 + srow;
        if (xrow >= M) continue;
        unsigned short* hp = h + (size_t)xrow * D;
#pragma unroll
        for (int nt = 0; nt < 16; ++nt) {
            const int wcol = nt * 16 + scol0;
            const f32x4 bv = *(const f32x4*)(b + wcol);
            u16x4 st;
            st[0] = f2bf(acc[t][nt][0] + bv[0]);
            st[1] = f2bf(acc[t][nt][1] + bv[1]);
            st[2] = f2bf(acc[t][nt][2] + bv[2]);
            st[3] = f2bf(acc[t][nt][3] + bv[3]);
            *(u16x4*)(hp + wcol) = st;
        }
    }
}

// ---------------------------------------------------------------------------
// K3: per-block bucket histogram (LDS only, no global atomics).
// ---------------------------------------------------------------------------
__global__ __launch_bounds__(256) void bucket_count(
    const int* __restrict__ adj_row, int* __restrict__ blk_hist, int E, int nbk)
{
    __shared__ int hist[MAXBK];
    const int tid = threadIdx.x;
    const int chunk = (E + PBLK - 1) / PBLK;
    const int e0 = blockIdx.x * chunk;
    const int e1 = min(e0 + chunk, E);

    for (int k = tid; k < nbk; k += 256) hist[k] = 0;
    __syncthreads();
    for (int i = e0 + tid; i < e1; i += 256)
        atomicAdd(&hist[adj_row[i] >> BSHIFT], 1);
    __syncthreads();
    for (int k = tid; k < nbk; k += 256)
        blk_hist[(size_t)blockIdx.x * nbk + k] = hist[k];
}

// ---------------------------------------------------------------------------
// K4: per bucket k, exclusive-scan blk_hist[:][k]; cnt[k] = total.
// ---------------------------------------------------------------------------
__global__ __launch_bounds__(256) void scan_blk_hist(
    int* __restrict__ blk_hist, int* __restrict__ cnt, int nbk)
{
    __shared__ int wsums[4];
    const int k = blockIdx.x;
    const int tid = threadIdx.x;
    const int lane = tid & 63;
    const int wid = tid >> 6;

    const int i0 = 2 * tid, i1 = 2 * tid + 1;
    const int h0 = blk_hist[(size_t)i0 * nbk + k];
    const int h1 = blk_hist[(size_t)i1 * nbk + k];
    const int tsum = h0 + h1;

    int v = tsum;
    for (int d = 1; d < 64; d <<= 1) {
        int u = __shfl_up(v, d, 64);
        if (lane >= d) v += u;
    }
    if (lane == 63) wsums[wid] = v;
    __syncthreads();
    int woff = 0;
    for (int w = 0; w < wid; ++w) woff += wsums[w];
    const int pref = woff + v - tsum;

    blk_hist[(size_t)i0 * nbk + k] = pref;
    blk_hist[(size_t)i1 * nbk + k] = pref + h0;
    if (tid == 0) cnt[k] = wsums[0] + wsums[1] + wsums[2] + wsums[3];
}

// ---------------------------------------------------------------------------
// K5: exclusive scan of cnt -> bbase. Single block, nbk <= 256.
// ---------------------------------------------------------------------------
__global__ __launch_bounds__(256) void scan_cnt(
    const int* __restrict__ cnt, int* __restrict__ bbase, int nbk)
{
    __shared__ int wsums[4];
    const int tid = threadIdx.x;
    const int lane = tid & 63;
    const int wid = tid >> 6;
    const int val = (tid < nbk) ? cnt[tid] : 0;

    int v = val;
    for (int d = 1; d < 64; d <<= 1) {
        int u = __shfl_up(v, d, 64);
        if (lane >= d) v += u;
    }
    if (lane == 63) wsums[wid] = v;
    __syncthreads();
    int woff = 0;
    for (int w = 0; w < wid; ++w) woff += wsums[w];
    if (tid < nbk) bbase[tid] = woff + v - val;
}

// ---------------------------------------------------------------------------
// K6: partition edges into bucket-grouped part[] with precomputed bases.
// ---------------------------------------------------------------------------
__global__ __launch_bounds__(256) void partition_edges(
    const int* __restrict__ adj_row, const int* __restrict__ adj_col,
    const float* __restrict__ adj_vals, const int* __restrict__ bbase,
    const int* __restrict__ blk_hist, uint2* __restrict__ part, int E, int nbk)
{
    __shared__ int sbase[MAXBK];
    __shared__ int lcur[MAXBK];

    const int tid = threadIdx.x;
    const int blk = blockIdx.x;
    const int chunk = (E + PBLK - 1) / PBLK;
    const int e0 = blk * chunk;
    const int e1 = min(e0 + chunk, E);

    for (int k = tid; k < nbk; k += 256) {
        sbase[k] = bbase[k] + blk_hist[(size_t)blk * nbk + k];
        lcur[k] = 0;
    }
    __syncthreads();

    for (int i = e0 + tid; i < e1; i += 256) {
        const int r = adj_row[i];
        const int k = r >> BSHIFT;
        const int col = __builtin_nontemporal_load(adj_col + i);
        const float val = __builtin_nontemporal_load(adj_vals + i);
        const int pos = sbase[k] + atomicAdd(&lcur[k], 1);
        part[pos] = make_uint2(((unsigned)(r & (BROWS - 1)) << 17) | (unsigned)col,
                               __float_as_uint(val));
    }
}

// ---------------------------------------------------------------------------
// K7: one block per bucket: local histogram + LDS scan -> row_ptr, then
// scatter part -> csr via LDS cursors.
// ---------------------------------------------------------------------------
__global__ __launch_bounds__(256) void bucket_fill(
    const uint2* __restrict__ part, const int* __restrict__ bbase,
    int* __restrict__ row_ptr, int2* __restrict__ csr, int n, int E, int nbk)
{
    __shared__ int hist[BROWS];
    __shared__ int off[BROWS];
    __shared__ int wsums[4];

    const int tid = threadIdx.x;
    const int lane = tid & 63;
    const int wid = tid >> 6;
    const int bk = blockIdx.x;
    const int row0 = bk << BSHIFT;
    const int nr = min(row0 + BROWS, n) - row0;
    const int base = bbase[bk];
    const int ecnt = ((bk + 1 < nbk) ? bbase[bk + 1] : E) - base;

    for (int r = tid; r < BROWS; r += 256) hist[r] = 0;
    __syncthreads();
    for (int i = tid; i < ecnt; i += 256)
        atomicAdd(&hist[part[base + i].x >> 17], 1);
    __syncthreads();

    const int h0 = hist[2 * tid], h1 = hist[2 * tid + 1];
    const int tsum = h0 + h1;
    int v = tsum;
    for (int d = 1; d < 64; d <<= 1) {
        int u = __shfl_up(v, d, 64);
        if (lane >= d) v += u;
    }
    if (lane == 63) wsums[wid] = v;
    __syncthreads();
    int woff = 0;
    for (int w = 0; w < wid; ++w) woff += wsums[w];
    const int pref = woff + v - tsum;
    off[2 * tid] = pref;
    off[2 * tid + 1] = pref + h0;
    __syncthreads();

    for (int r = tid; r < nr; r += 256) row_ptr[row0 + r] = base + off[r];
    if (bk == nbk - 1 && tid == 0) row_ptr[n] = E;
    for (int r = tid; r < BROWS; r += 256) hist[r] = base + off[r];
    __syncthreads();

    for (int i = tid; i < ecnt; i += 256) {
        const uint2 w = part[base + i];
        const int lr = w.x >> 17;
        const int pos = atomicAdd(&hist[lr], 1);
        csr[pos] = make_int2((int)(w.x & 0x1FFFF), (int)w.y);
    }
}

// ---------------------------------------------------------------------------
// K8/K9: gather over one col-half (128 cols) of bf16 h + fused ReLU.
// ---------------------------------------------------------------------------
__global__ __launch_bounds__(256) void gather_half(
    const int* __restrict__ row_ptr, const int2* __restrict__ csr,
    const unsigned short* __restrict__ h, float* __restrict__ out, int n, int c0)
{
    const int row = blockIdx.x * 4 + (threadIdx.x >> 6);
    if (row >= n) return;
    const int lane = threadIdx.x & 63;
    const int half = lane >> 5;
    const int l32 = lane & 31;

    const int s = row_ptr[row];
    const int e = row_ptr[row + 1];

    float a0 = 0.f, a1 = 0.f, a2 = 0.f, a3 = 0.f;

    for (int i = s; i < e; i += 4) {
        const int idx0 = i + half;
        const int idx1 = i + 2 + half;
        const bool v0ok = idx0 < e;
        const bool v1ok = idx1 < e;
        const int2 cv0 = csr[v0ok ? idx0 : s];
        const int2 cv1 = csr[v1ok ? idx1 : s];
        const float v0 = v0ok ? __int_as_float(cv0.y) : 0.f;
        const float v1 = v1ok ? __int_as_float(cv1.y) : 0.f;
        const uint2 d0 = ((const uint2*)(h + (size_t)cv0.x * D + c0))[l32];
        const uint2 d1 = ((const uint2*)(h + (size_t)cv1.x * D + c0))[l32];
        a0 += v0 * bf_lo(d0.x) + v1 * bf_lo(d1.x);
        a1 += v0 * bf_hi(d0.x) + v1 * bf_hi(d1.x);
        a2 += v0 * bf_lo(d0.y) + v1 * bf_lo(d1.y);
        a3 += v0 * bf_hi(d0.y) + v1 * bf_hi(d1.y);
    }

    a0 += __shfl_xor(a0, 32, 64);
    a1 += __shfl_xor(a1, 32, 64);
    a2 += __shfl_xor(a2, 32, 64);
    a3 += __shfl_xor(a3, 32, 64);

    if (half == 0) {
        f32x4 st;
        st[0] = fmaxf(a0, 0.f); st[1] = fmaxf(a1, 0.f);
        st[2] = fmaxf(a2, 0.f); st[3] = fmaxf(a3, 0.f);
        __builtin_nontemporal_store(st, (f32x4*)(out + (size_t)row * D + c0) + l32);
    }
}

// ---------------------------------------------------------------------------
extern "C" void kernel_launch(void* const* d_in, const int* in_sizes, int n_in,
                              void* d_out, int out_size, void* d_ws, size_t ws_size,
                              hipStream_t stream)
{
    const float* x        = (const float*)d_in[0];
    const int*   adj_row  = (const int*)d_in[1];
    const int*   adj_col  = (const int*)d_in[2];
    const float* adj_vals = (const float*)d_in[3];
    const float* W        = (const float*)d_in[4];
    const float* b        = (const float*)d_in[5];
    float*       out      = (float*)d_out;

    const int n = in_sizes[0] / D;               // 100000 nodes
    const int E = in_sizes[1];                   // 3.2M edges
    const int nbk = (n + BROWS - 1) >> BSHIFT;   // buckets (196)

    char* ws = (char*)d_ws;
    size_t off = 0;
    auto alloc = [&](size_t bytes) {
        size_t o = off;
        off += (bytes + 255) & ~(size_t)255;
        return o;
    };
    unsigned short* h  = (unsigned short*)(ws + alloc((size_t)n * D * sizeof(unsigned short)));
    unsigned short* Wp = (unsigned short*)(ws + alloc((size_t)8192 * 8 * sizeof(unsigned short)));
    int*   blk_hist = (int*)  (ws + alloc((size_t)PBLK * nbk * sizeof(int)));
    int*   cnt      = (int*)  (ws + alloc((size_t)MAXBK * sizeof(int)));
    int*   bbase    = (int*)  (ws + alloc((size_t)MAXBK * sizeof(int)));
    int*   row_ptr  = (int*)  (ws + alloc((size_t)(n + 1) * sizeof(int)));
    uint2* part     = (uint2*)(ws + alloc((size_t)E * sizeof(uint2)));
    int2*  csr      = (int2*) (ws + alloc((size_t)E * sizeof(int2)));
    (void)ws_size;

    // linear
    pack_W<<<32, 256, 0, stream>>>(W, Wp);
    mfma_linear<<<(n + 127) / 128, 256, 0, stream>>>(x, Wp, b, h, n);

    // CSR build — atomic-free (LDS histograms + deterministic scans)
    bucket_count<<<PBLK, 256, 0, stream>>>(adj_row, blk_hist, E, nbk);
    scan_blk_hist<<<nbk, 256, 0, stream>>>(blk_hist, cnt, nbk);
    scan_cnt<<<1, 256, 0, stream>>>(cnt, bbase, nbk);
    partition_edges<<<PBLK, 256, 0, stream>>>(adj_row, adj_col, adj_vals, bbase, blk_hist, part, E, nbk);
    bucket_fill<<<nbk, 256, 0, stream>>>(part, bbase, row_ptr, csr, n, E, nbk);

    // fused gather + ReLU, two sequential col-half passes for L3 residency
    gather_half<<<(n + 3) / 4, 256, 0, stream>>>(row_ptr, csr, h, out, n, 0);
    gather_half<<<(n + 3) / 4, 256, 0, stream>>>(row_ptr, csr, h, out, n, 128);
}